// Round 2
// baseline (743.231 us; speedup 1.0000x reference)
//
#include <hip/hip_runtime.h>
#include <hip/hip_bf16.h>
#include <math.h>

constexpr int kN = 10000;   // nodes
constexpr int kE = 160000;  // edges
constexpr float kSlope = 0.2f;

__device__ __forceinline__ float lrelu(float x) { return x > 0.f ? x : kSlope * x; }
__device__ __forceinline__ float elu_f(float x) { return x > 0.f ? x : (expf(x) - 1.f); }
__device__ __forceinline__ float bfu(unsigned short u) {
    return __uint_as_float(((unsigned)u) << 16);
}

// ---------------- runtime dtype detection (device-side, graph-safe) ----------------
// flags[0] = 1 if float tensors are f32 (else bf16); flags[1] = 1 if indices are int64
__global__ void detect_flags(const void* __restrict__ x, const void* __restrict__ dsti,
                             int* __restrict__ flags) {
    __shared__ int sb[2];
    int tid = threadIdx.x;
    if (tid == 0) { sb[0] = 0; sb[1] = 0; }
    __syncthreads();
    const unsigned short* xb = (const unsigned short*)x;
    int big = 0;
    for (int i = tid; i < 4096; i += 256) {
        float v = bfu(xb[i]);
        if (!(fabsf(v) <= 1e4f)) big = 1;   // catches huge + NaN -> underlying data is f32
    }
    const int* d32 = (const int*)dsti;
    int hi = 0;
    for (int i = tid; i < 4096; i += 256) hi |= d32[2 * i + 1];
    if (big) atomicOr(&sb[0], 1);
    if (hi)  atomicOr(&sb[1], 1);
    __syncthreads();
    if (tid == 0) { flags[0] = sb[0]; flags[1] = sb[1] ? 0 : 1; }
}

__global__ void zero_ints(int* __restrict__ p, int n) {
    int i = blockIdx.x * 256 + threadIdx.x;
    if (i < n) p[i] = 0;
}

// normalize indices to clamped int32
__global__ void norm_idx(const void* __restrict__ in, int* __restrict__ out, int n,
                         const int* __restrict__ flags) {
    int i = blockIdx.x * 256 + threadIdx.x;
    if (i >= n) return;
    int v = flags[1] ? (int)((const long long*)in)[i] : ((const int*)in)[i];
    out[i] = ((unsigned)v < (unsigned)kN) ? v : 0;
}

// convert float tensor (bf16 or f32 per flag) to f32
__global__ void cvt_any(const void* __restrict__ in, float* __restrict__ out, int n,
                        const int* __restrict__ flags) {
    int i = blockIdx.x * 256 + threadIdx.x;
    if (i >= n) return;
    if (flags[0]) out[i] = ((const float*)in)[i];
    else          out[i] = bfu(((const unsigned short*)in)[i]);
}

// ---------------- CSR build ----------------
__global__ void count_deg(const int* __restrict__ dst, int* __restrict__ deg, int n) {
    int i = blockIdx.x * 256 + threadIdx.x;
    if (i < n) atomicAdd(&deg[dst[i]], 1);
}

__global__ __launch_bounds__(1024) void scan_off(const int* __restrict__ deg,
                                                 int* __restrict__ off, int n) {
    __shared__ int s[1024];
    int tid = threadIdx.x;
    int per = (n + 1023) >> 10;
    int base = tid * per;
    int sum = 0;
    for (int i = 0; i < per; ++i) { int j = base + i; if (j < n) sum += deg[j]; }
    s[tid] = sum;
    __syncthreads();
    for (int d = 1; d < 1024; d <<= 1) {
        int v = (tid >= d) ? s[tid - d] : 0;
        __syncthreads();
        s[tid] += v;
        __syncthreads();
    }
    int run = (tid > 0) ? s[tid - 1] : 0;
    for (int i = 0; i < per; ++i) {
        int j = base + i;
        if (j < n) { off[j] = run; run += deg[j]; }
    }
    if (tid == 0) off[n] = s[1023];
}

__global__ void fill_csr(const int* __restrict__ src, const int* __restrict__ dst,
                         const int* __restrict__ off, int* __restrict__ cnt,
                         int* __restrict__ srcsorted, int n) {
    int i = blockIdx.x * 256 + threadIdx.x;
    if (i < n) {
        int d = dst[i];
        int pos = off[d] + atomicAdd(&cnt[d], 1);
        if (pos < kE) srcsorted[pos] = src[i];
    }
}

// ---------------- generic f32 GEMM: C[M,N] = A[M,K] @ B[K,N] ----------------
__global__ __launch_bounds__(256) void gemm_f32(const float* __restrict__ A,
                                                const float* __restrict__ B,
                                                float* __restrict__ C,
                                                int M, int N, int K) {
    __shared__ float As[16][64];
    __shared__ float Bs[16][64];
    const int t  = threadIdx.x;
    const int tx = t & 15;
    const int ty = t >> 4;
    const int row0 = blockIdx.y * 64;
    const int col0 = blockIdx.x * 64;
    const int ar = t >> 2;
    const int ak = (t & 3) * 4;
    const int bk = t >> 4;
    const int bc = (t & 15) * 4;

    float acc[4][4] = {};
    for (int k0 = 0; k0 < K; k0 += 16) {
        float4 av;
        if (row0 + ar < M) av = *(const float4*)(A + (size_t)(row0 + ar) * K + k0 + ak);
        else av = make_float4(0.f, 0.f, 0.f, 0.f);
        As[ak + 0][ar] = av.x; As[ak + 1][ar] = av.y;
        As[ak + 2][ar] = av.z; As[ak + 3][ar] = av.w;
        float4 bv = *(const float4*)(B + (size_t)(k0 + bk) * N + col0 + bc);
        *(float4*)&Bs[bk][bc] = bv;
        __syncthreads();
#pragma unroll
        for (int kk = 0; kk < 16; ++kk) {
            float a[4], b[4];
#pragma unroll
            for (int i = 0; i < 4; ++i) a[i] = As[kk][ty * 4 + i];
#pragma unroll
            for (int j = 0; j < 4; ++j) b[j] = Bs[kk][tx * 4 + j];
#pragma unroll
            for (int i = 0; i < 4; ++i)
#pragma unroll
                for (int j = 0; j < 4; ++j) acc[i][j] += a[i] * b[j];
        }
        __syncthreads();
    }
#pragma unroll
    for (int i = 0; i < 4; ++i) {
        int r = row0 + ty * 4 + i;
        if (r < M) {
#pragma unroll
            for (int j = 0; j < 4; ++j)
                C[(size_t)r * N + col0 + tx * 4 + j] = acc[i][j];
        }
    }
}

// ---------------- el/er per node per head ----------------
__global__ __launch_bounds__(256) void compute_eler(const float* __restrict__ feat,
                                                    const float* __restrict__ al,
                                                    const float* __restrict__ ar,
                                                    float* __restrict__ el,
                                                    float* __restrict__ er) {
    int n = blockIdx.x;
    int h = threadIdx.x >> 6;
    int lane = threadIdx.x & 63;
    const float* f = feat + (size_t)n * 512 + h * 128;
    const float* a = al + h * 128;
    const float* r = ar + h * 128;
    float accl = f[lane] * a[lane] + f[lane + 64] * a[lane + 64];
    float accr = f[lane] * r[lane] + f[lane + 64] * r[lane + 64];
    for (int o = 32; o > 0; o >>= 1) {
        accl += __shfl_down(accl, o);
        accr += __shfl_down(accr, o);
    }
    if (lane == 0) { el[n * 4 + h] = accl; er[n * 4 + h] = accr; }
}

// ---------------- GAT softmax + aggregation per destination node ----------------
template <bool RES, bool ACT>
__global__ __launch_bounds__(256) void gat_agg(const float* __restrict__ feat,
                                               const float* __restrict__ el,
                                               const float* __restrict__ er,
                                               const int* __restrict__ off,
                                               const int* __restrict__ srcsorted,
                                               const float* __restrict__ resid,
                                               const float* __restrict__ bias,
                                               float* __restrict__ out) {
    __shared__ float4 red[256];
    __shared__ float wbuf[64 * 4];
    __shared__ int sl[64];
    const int n = blockIdx.x;
    const int tid = threadIdx.x;
    const int off0 = off[n];
    const int deg = off[n + 1] - off0;
    float4 er4 = *(const float4*)(er + n * 4);

    float m0 = -1e30f, m1 = -1e30f, m2 = -1e30f, m3 = -1e30f;
    for (int i = tid; i < deg; i += 256) {
        int s = srcsorted[off0 + i];
        float4 ev = *(const float4*)(el + s * 4);
        m0 = fmaxf(m0, lrelu(ev.x + er4.x));
        m1 = fmaxf(m1, lrelu(ev.y + er4.y));
        m2 = fmaxf(m2, lrelu(ev.z + er4.z));
        m3 = fmaxf(m3, lrelu(ev.w + er4.w));
    }
    red[tid] = make_float4(m0, m1, m2, m3);
    __syncthreads();
    for (int st = 128; st > 0; st >>= 1) {
        if (tid < st) {
            float4 a = red[tid], b = red[tid + st];
            red[tid] = make_float4(fmaxf(a.x, b.x), fmaxf(a.y, b.y),
                                   fmaxf(a.z, b.z), fmaxf(a.w, b.w));
        }
        __syncthreads();
    }
    float4 mm = red[0];
    __syncthreads();

    float s0 = 0.f, s1 = 0.f, s2 = 0.f, s3 = 0.f;
    for (int i = tid; i < deg; i += 256) {
        int s = srcsorted[off0 + i];
        float4 ev = *(const float4*)(el + s * 4);
        s0 += expf(lrelu(ev.x + er4.x) - mm.x);
        s1 += expf(lrelu(ev.y + er4.y) - mm.y);
        s2 += expf(lrelu(ev.z + er4.z) - mm.z);
        s3 += expf(lrelu(ev.w + er4.w) - mm.w);
    }
    red[tid] = make_float4(s0, s1, s2, s3);
    __syncthreads();
    for (int st = 128; st > 0; st >>= 1) {
        if (tid < st) {
            float4 a = red[tid], b = red[tid + st];
            red[tid] = make_float4(a.x + b.x, a.y + b.y, a.z + b.z, a.w + b.w);
        }
        __syncthreads();
    }
    float4 dd = red[0];
    dd.x = fmaxf(dd.x, 1e-9f); dd.y = fmaxf(dd.y, 1e-9f);
    dd.z = fmaxf(dd.z, 1e-9f); dd.w = fmaxf(dd.w, 1e-9f);
    __syncthreads();

    const int p0 = tid;
    const int p1 = tid + 256;
    const int h0 = tid >> 7;
    const int h1 = 2 + (tid >> 7);
    float acc0 = 0.f, acc1 = 0.f;
    for (int c = 0; c < deg; c += 64) {
        int cl = min(64, deg - c);
        __syncthreads();
        {
            int i = tid >> 2, h = tid & 3;
            if (i < cl) {
                int s = srcsorted[off0 + c + i];
                if (h == 0) sl[i] = s;
                float ev = el[s * 4 + h];
                float erh = (h == 0) ? er4.x : (h == 1) ? er4.y : (h == 2) ? er4.z : er4.w;
                float mh  = (h == 0) ? mm.x : (h == 1) ? mm.y : (h == 2) ? mm.z : mm.w;
                float dh  = (h == 0) ? dd.x : (h == 1) ? dd.y : (h == 2) ? dd.z : dd.w;
                wbuf[i * 4 + h] = expf(lrelu(ev + erh) - mh) / dh;
            }
        }
        __syncthreads();
        for (int i2 = 0; i2 < cl; ++i2) {
            int s = sl[i2];
            float w0 = wbuf[i2 * 4 + h0];
            float w1 = wbuf[i2 * 4 + h1];
            acc0 += w0 * feat[(size_t)s * 512 + p0];
            acc1 += w1 * feat[(size_t)s * 512 + p1];
        }
    }
    float v0 = acc0 + bias[p0];
    float v1 = acc1 + bias[p1];
    if (RES) { v0 += resid[(size_t)n * 512 + p0]; v1 += resid[(size_t)n * 512 + p1]; }
    if (ACT) { v0 = elu_f(v0); v1 = elu_f(v1); }
    out[(size_t)n * 512 + p0] = v0;
    out[(size_t)n * 512 + p1] = v1;
}

// ---------------- mean over heads ----------------
__global__ void mean_heads(const float* __restrict__ rst, float* __restrict__ hmean) {
    int n = blockIdx.x, d = threadIdx.x;
    const float* r = rst + (size_t)n * 512;
    hmean[(size_t)n * 128 + d] = 0.25f * (r[d] + r[128 + d] + r[256 + d] + r[384 + d]);
}

// ---------------- fused edge MLP ----------------
__global__ __launch_bounds__(256) void edge_mlp(const float* __restrict__ P,
                                                const float* __restrict__ Q,
                                                const float* __restrict__ bm0,
                                                const float* __restrict__ Wm1,
                                                const float* __restrict__ bm1,
                                                const float* __restrict__ Wm2,
                                                const float* __restrict__ bm2,
                                                const int* __restrict__ src,
                                                const int* __restrict__ dst,
                                                void* __restrict__ outv,
                                                const int* __restrict__ flags,
                                                int E) {
    __shared__ float sW1[128 * 64];
    __shared__ float sW2[64];
    __shared__ float sb0[128];
    __shared__ float sb1[64];
    __shared__ float z0s[4][128];
    const int tid = threadIdx.x;
    for (int i = tid; i < 128 * 64; i += 256) sW1[i] = Wm1[i];
    if (tid < 64) { sW2[tid] = Wm2[tid]; sb1[tid] = bm1[tid]; }
    if (tid < 128) sb0[tid] = bm0[tid];
    __syncthreads();
    const int wave = tid >> 6, lane = tid & 63;
    const int gw = blockIdx.x * 4 + wave;
    const int total = gridDim.x * 4;
    const int iters = (E + total - 1) / total;
    const float b2 = bm2[0];
    const int f32out = flags[0];
    for (int it = 0; it < iters; ++it) {
        int e = gw + it * total;
        bool valid = e < E;
        if (valid) {
            int s = src[e], d = dst[e];
            float z0a = fmaxf(P[(size_t)s * 128 + lane] + Q[(size_t)d * 128 + lane] + sb0[lane], 0.f);
            float z0b = fmaxf(P[(size_t)s * 128 + 64 + lane] + Q[(size_t)d * 128 + 64 + lane] + sb0[64 + lane], 0.f);
            z0s[wave][lane] = z0a;
            z0s[wave][64 + lane] = z0b;
        }
        __syncthreads();
        if (valid) {
            float acc = sb1[lane];
#pragma unroll 8
            for (int k = 0; k < 128; ++k) acc += z0s[wave][k] * sW1[k * 64 + lane];
            acc = fmaxf(acc, 0.f);
            float tsum = acc * sW2[lane];
            for (int o = 32; o > 0; o >>= 1) tsum += __shfl_down(tsum, o);
            if (lane == 0) {
                float r = 1.f / (1.f + expf(-(tsum + b2)));
                if (f32out) ((float*)outv)[e] = r;
                else        ((__hip_bfloat16*)outv)[e] = __float2bfloat16(r);
            }
        }
        __syncthreads();
    }
}

// ---------------- host launch ----------------
extern "C" void kernel_launch(void* const* d_in, const int* in_sizes, int n_in,
                              void* d_out, int out_size, void* d_ws, size_t ws_size,
                              hipStream_t stream) {
    (void)in_sizes; (void)n_in; (void)out_size; (void)ws_size;

    float* w = (float*)d_ws;
    size_t o = 0;
    auto alloc = [&](size_t n) { float* p = w + o; o += (n + 3) & ~size_t(3); return p; };
    // weights (f32 canonical)
    float* w0f  = alloc(256 * 512);
    float* w1f  = alloc(512 * 512);
    float* w2f  = alloc(512 * 512);
    float* wm0f = alloc(256 * 128);
    float* al0f = alloc(512); float* ar0f = alloc(512); float* b0f = alloc(512);
    float* al1f = alloc(512); float* ar1f = alloc(512); float* b1f = alloc(512);
    float* al2f = alloc(512); float* ar2f = alloc(512); float* b2f = alloc(512);
    float* bm0f = alloc(128);
    float* wm1f = alloc(128 * 64); float* bm1f = alloc(64);
    float* wm2f = alloc(64);       float* bm2f = alloc(4);
    float* elb  = alloc((size_t)kN * 4);
    float* erb  = alloc((size_t)kN * 4);
    // big buffers (reused)
    float* feat = alloc((size_t)kN * 512);   // also hmean/P/Q later
    float* h0   = alloc((size_t)kN * 512);   // layer0 out; layer2 out
    float* h1   = alloc((size_t)kN * 512);   // xf (layer0 input) first, then layer1 out
    // ints
    int* ip    = (int*)(w + o);
    int* flags = ip;            // 4
    int* deg   = ip + 4;
    int* cnt   = deg + kN;
    int* off   = cnt + kN;                     // kN+1 (padded to 10004)
    int* ss    = off + 10004;                  // kE
    int* nsrc  = ss + kE;
    int* ndst  = nsrc + kE;

    float* xf    = h1;                 // 2.56M <= 5.12M
    float* hmean = feat;               // 1.28M
    float* Pb    = feat + 1280000;
    float* Qb    = feat + 2560000;

    dim3 blk(256);

    // 0) dtype detection + index normalization
    detect_flags<<<dim3(1), blk, 0, stream>>>(d_in[0], d_in[2], flags);
    norm_idx<<<dim3((kE + 255) / 256), blk, 0, stream>>>(d_in[1], nsrc, kE, flags);
    norm_idx<<<dim3((kE + 255) / 256), blk, 0, stream>>>(d_in[2], ndst, kE, flags);

    auto cvt = [&](int idx, float* dstp, int n) {
        cvt_any<<<dim3((n + 255) / 256), blk, 0, stream>>>(d_in[idx], dstp, n, flags);
    };
    cvt(0, xf, kN * 256);
    cvt(3, w0f, 256 * 512);  cvt(4, al0f, 512); cvt(5, ar0f, 512); cvt(6, b0f, 512);
    cvt(7, w1f, 512 * 512);  cvt(8, al1f, 512); cvt(9, ar1f, 512); cvt(10, b1f, 512);
    cvt(11, w2f, 512 * 512); cvt(12, al2f, 512); cvt(13, ar2f, 512); cvt(14, b2f, 512);
    cvt(15, wm0f, 256 * 128); cvt(16, bm0f, 128);
    cvt(17, wm1f, 128 * 64);  cvt(18, bm1f, 64);
    cvt(19, wm2f, 64);        cvt(20, bm2f, 1);

    // 1) CSR build
    zero_ints<<<dim3((2 * kN + 255) / 256), blk, 0, stream>>>(deg, 2 * kN);  // deg + cnt
    count_deg<<<dim3((kE + 255) / 256), blk, 0, stream>>>(ndst, deg, kE);
    scan_off<<<dim3(1), dim3(1024), 0, stream>>>(deg, off, kN);
    fill_csr<<<dim3((kE + 255) / 256), blk, 0, stream>>>(nsrc, ndst, off, cnt, ss, kE);

    auto gemm = [&](const float* A, const float* B, float* C, int M, int N, int K) {
        gemm_f32<<<dim3(N / 64, (M + 63) / 64), blk, 0, stream>>>(A, B, C, M, N, K);
    };

    // 2) Layer 0: in=256, out=4x128, no residual, ELU
    gemm(xf, w0f, feat, kN, 512, 256);
    compute_eler<<<dim3(kN), blk, 0, stream>>>(feat, al0f, ar0f, elb, erb);
    gat_agg<false, true><<<dim3(kN), blk, 0, stream>>>(feat, elb, erb, off, ss, nullptr, b0f, h0);

    // 3) Layer 1: residual, ELU  (h1 overwrites xf — xf dead after layer-0 gemm)
    gemm(h0, w1f, feat, kN, 512, 512);
    compute_eler<<<dim3(kN), blk, 0, stream>>>(feat, al1f, ar1f, elb, erb);
    gat_agg<true, true><<<dim3(kN), blk, 0, stream>>>(feat, elb, erb, off, ss, h0, b1f, h1);

    // 4) Layer 2: residual, no act (out -> h0, free by now)
    gemm(h1, w2f, feat, kN, 512, 512);
    compute_eler<<<dim3(kN), blk, 0, stream>>>(feat, al2f, ar2f, elb, erb);
    gat_agg<true, false><<<dim3(kN), blk, 0, stream>>>(feat, elb, erb, off, ss, h1, b2f, h0);

    // 5) mean over heads -> hmean (in feat, which is free now)
    mean_heads<<<dim3(kN), dim3(128), 0, stream>>>(h0, hmean);

    // 6) P = hmean @ Wm0[:128,:], Q = hmean @ Wm0[128:,:]
    gemm(hmean, wm0f, Pb, kN, 128, 128);
    gemm(hmean, wm0f + 128 * 128, Qb, kN, 128, 128);

    // 7) fused edge MLP + sigmoid (+ dtype-matched output write)
    edge_mlp<<<dim3(1024), blk, 0, stream>>>(Pb, Qb, bm0f, wm1f, bm1f, wm2f, bm2f,
                                             nsrc, ndst, d_out, flags, kE);
}

// Round 4
// 688.448 us; speedup vs baseline: 1.0796x; 1.0796x over previous
//
#include <hip/hip_runtime.h>
#include <hip/hip_bf16.h>
#include <math.h>

constexpr int kN = 10000;   // nodes
constexpr int kE = 160000;  // edges
constexpr float kSlope = 0.2f;

typedef short v8s __attribute__((ext_vector_type(8)));
typedef float f32x4 __attribute__((ext_vector_type(4)));

__device__ __forceinline__ float lrelu(float x) { return x > 0.f ? x : kSlope * x; }
__device__ __forceinline__ float elu_f(float x) { return x > 0.f ? x : (expf(x) - 1.f); }
__device__ __forceinline__ float b2f(unsigned short u) {
    return __uint_as_float(((unsigned)u) << 16);
}
__device__ __forceinline__ unsigned short f2b(float f) {   // RNE f32->bf16
    unsigned u = __float_as_uint(f);
    return (unsigned short)((u + 0x7FFFu + ((u >> 16) & 1u)) >> 16);
}

// ---------------- runtime dtype detection ----------------
__global__ void detect_flags(const void* __restrict__ x, const void* __restrict__ dsti,
                             int* __restrict__ flags) {
    __shared__ int sb[2];
    int tid = threadIdx.x;
    if (tid == 0) { sb[0] = 0; sb[1] = 0; }
    __syncthreads();
    const unsigned short* xb = (const unsigned short*)x;
    int big = 0;
    for (int i = tid; i < 4096; i += 256) {
        float v = b2f(xb[i]);
        if (!(fabsf(v) <= 1e4f)) big = 1;
    }
    const int* d32 = (const int*)dsti;
    int hi = 0;
    for (int i = tid; i < 4096; i += 256) hi |= d32[2 * i + 1];
    if (big) atomicOr(&sb[0], 1);
    if (hi)  atomicOr(&sb[1], 1);
    __syncthreads();
    if (tid == 0) { flags[0] = sb[0]; flags[1] = sb[1] ? 0 : 1; }
}

// ---------------- MFMA layout probe ----------------
__device__ __forceinline__ int pavA(int m, int k) { return ((m * 3 + k * 5) % 7) - 3; }
__device__ __forceinline__ int pavB(int k, int n) { return ((k * 2 + n * 11) % 5) - 2; }

__global__ void mfma_probe(int* __restrict__ flags) {
    int lane = threadIdx.x & 63;
    int l16 = lane & 15, q = lane >> 4;
    v8s a, b;
#pragma unroll
    for (int j = 0; j < 8; ++j) {
        int k = q * 8 + j;
        a[j] = (short)f2b((float)pavA(l16, k));
        b[j] = (short)f2b((float)pavB(k, l16));
    }
    f32x4 acc = {0.f, 0.f, 0.f, 0.f};
    acc = __builtin_amdgcn_mfma_f32_16x16x32_bf16(a, b, acc, 0, 0, 0);
    bool ok = true;
#pragma unroll
    for (int r = 0; r < 4; ++r) {
        int row = q * 4 + r, col = l16;
        float e = 0.f;
        for (int k = 0; k < 32; ++k) e += (float)(pavA(row, k) * pavB(k, col));
        ok = ok && (fabsf(acc[r] - e) < 0.5f);
    }
    unsigned long long bal = __ballot(ok);
    if (lane == 0) flags[2] = (bal == ~0ull) ? 1 : 0;
}

__global__ void zero_ints(int* __restrict__ p, int n) {
    int i = blockIdx.x * 256 + threadIdx.x;
    if (i < n) p[i] = 0;
}

__global__ void norm_idx(const void* __restrict__ in, int* __restrict__ out, int n,
                         const int* __restrict__ flags) {
    int i = blockIdx.x * 256 + threadIdx.x;
    if (i >= n) return;
    int v = flags[1] ? (int)((const long long*)in)[i] : ((const int*)in)[i];
    out[i] = ((unsigned)v < (unsigned)kN) ? v : 0;
}

__global__ void cvt_any(const void* __restrict__ in, float* __restrict__ out, int n,
                        const int* __restrict__ flags) {
    int i = blockIdx.x * 256 + threadIdx.x;
    if (i >= n) return;
    if (flags[0]) out[i] = ((const float*)in)[i];
    else          out[i] = b2f(((const unsigned short*)in)[i]);
}

__global__ void xprep(const void* __restrict__ in, unsigned short* __restrict__ out, int n,
                      const int* __restrict__ flags) {
    int i = blockIdx.x * 256 + threadIdx.x;
    if (i >= n) return;
    out[i] = flags[0] ? f2b(((const float*)in)[i]) : ((const unsigned short*)in)[i];
}

// f32 [M,512] -> bf16 hi|lo [M,1024]
__global__ void hilo512(const float* __restrict__ in, unsigned short* __restrict__ out, int total) {
    int i = blockIdx.x * 256 + threadIdx.x;
    if (i >= total) return;
    int row = i >> 9, c = i & 511;
    float v = in[i];
    unsigned short h = f2b(v);
    out[(size_t)row * 1024 + c] = h;
    out[(size_t)row * 1024 + 512 + c] = f2b(v - b2f(h));
}

// head-mean f32 [N,4,128] -> f32 [N,128]
__global__ void mean_heads(const float* __restrict__ rst, float* __restrict__ hmean) {
    int n = blockIdx.x, d = threadIdx.x;
    const float* r = rst + (size_t)n * 512;
    hmean[(size_t)n * 128 + d] = 0.25f * (r[d] + r[128 + d] + r[256 + d] + r[384 + d]);
}

// head-mean f32 [N,4,128] -> bf16 hi|lo [N,256]
__global__ void meanhilo(const float* __restrict__ in, unsigned short* __restrict__ out) {
    int n = blockIdx.x, c = threadIdx.x;   // 128 threads
    const float* r = in + (size_t)n * 512;
    float v = 0.25f * (r[c] + r[128 + c] + r[256 + c] + r[384 + c]);
    unsigned short h = f2b(v);
    out[(size_t)n * 256 + c] = h;
    out[(size_t)n * 256 + 128 + c] = f2b(v - b2f(h));
}

// WT[n*Kout + k] = W[(k % Ksrc)*N + n]  (bf16 transpose, optional hi/lo K-doubling)
__global__ void wtprep(const void* __restrict__ W, unsigned short* __restrict__ WT,
                       int N, int Ksrc, int Kout, const int* __restrict__ flags) {
    int idx = blockIdx.x * 256 + threadIdx.x;
    if (idx >= N * Kout) return;
    int n = idx / Kout, k = idx - n * Kout;
    int srcidx = (k % Ksrc) * N + n;
    unsigned short v = flags[0] ? f2b(((const float*)W)[srcidx])
                                : ((const unsigned short*)W)[srcidx];
    WT[(size_t)n * Kout + k] = v;
}

// PQT[n*256 + k]: combined P|Q weight transpose (hi/lo stacked K=256)
__global__ void pqt_prep(const void* __restrict__ Wm0, unsigned short* __restrict__ PQT,
                         const int* __restrict__ flags) {
    int idx = blockIdx.x * 256 + threadIdx.x;
    if (idx >= 256 * 256) return;
    int n = idx >> 8, k = idx & 255;
    int srcidx = ((k & 127) + ((n < 128) ? 0 : 128)) * 128 + (n & 127);
    unsigned short v = flags[0] ? f2b(((const float*)Wm0)[srcidx])
                                : ((const unsigned short*)Wm0)[srcidx];
    PQT[idx] = v;
}

// Wpq f32 [128,256] fallback combined weight
__global__ void wpq_prep(const void* __restrict__ Wm0, float* __restrict__ Wpq,
                         const int* __restrict__ flags) {
    int idx = blockIdx.x * 256 + threadIdx.x;
    if (idx >= 128 * 256) return;
    int r = idx >> 8, c = idx & 255;
    int srcidx = (r + (c < 128 ? 0 : 128)) * 128 + (c & 127);
    Wpq[idx] = flags[0] ? ((const float*)Wm0)[srcidx] : b2f(((const unsigned short*)Wm0)[srcidx]);
}

// ---------------- CSR build ----------------
__global__ void count_deg(const int* __restrict__ dst, int* __restrict__ deg, int n) {
    int i = blockIdx.x * 256 + threadIdx.x;
    if (i < n) atomicAdd(&deg[dst[i]], 1);
}

__global__ __launch_bounds__(1024) void scan_off(const int* __restrict__ deg,
                                                 int* __restrict__ off, int n) {
    __shared__ int s[1024];
    int tid = threadIdx.x;
    int per = (n + 1023) >> 10;
    int base = tid * per;
    int sum = 0;
    for (int i = 0; i < per; ++i) { int j = base + i; if (j < n) sum += deg[j]; }
    s[tid] = sum;
    __syncthreads();
    for (int d = 1; d < 1024; d <<= 1) {
        int v = (tid >= d) ? s[tid - d] : 0;
        __syncthreads();
        s[tid] += v;
        __syncthreads();
    }
    int run = (tid > 0) ? s[tid - 1] : 0;
    for (int i = 0; i < per; ++i) {
        int j = base + i;
        if (j < n) { off[j] = run; run += deg[j]; }
    }
    if (tid == 0) off[n] = s[1023];
}

__global__ void fill_csr(const int* __restrict__ src, const int* __restrict__ dst,
                         const int* __restrict__ off, int* __restrict__ cnt,
                         int* __restrict__ srcsorted, int n) {
    int i = blockIdx.x * 256 + threadIdx.x;
    if (i < n) {
        int d = dst[i];
        int pos = off[d] + atomicAdd(&cnt[d], 1);
        if (pos < kE) srcsorted[pos] = src[i];
    }
}

// ---------------- fallback f32 GEMM (round-2 proven), gated off when MFMA ok ----------------
__global__ __launch_bounds__(256) void gemm_f32(const float* __restrict__ A,
                                                const float* __restrict__ B,
                                                float* __restrict__ C,
                                                int M, int N, int K,
                                                const int* __restrict__ flags) {
    if (flags[2] == 1) return;
    __shared__ float As[16][64];
    __shared__ float Bs[16][64];
    const int t  = threadIdx.x;
    const int tx = t & 15;
    const int ty = t >> 4;
    const int row0 = blockIdx.y * 64;
    const int col0 = blockIdx.x * 64;
    const int ar = t >> 2;
    const int ak = (t & 3) * 4;
    const int bk = t >> 4;
    const int bc = (t & 15) * 4;

    float acc[4][4] = {};
    for (int k0 = 0; k0 < K; k0 += 16) {
        float4 av;
        if (row0 + ar < M) av = *(const float4*)(A + (size_t)(row0 + ar) * K + k0 + ak);
        else av = make_float4(0.f, 0.f, 0.f, 0.f);
        As[ak + 0][ar] = av.x; As[ak + 1][ar] = av.y;
        As[ak + 2][ar] = av.z; As[ak + 3][ar] = av.w;
        float4 bv = *(const float4*)(B + (size_t)(k0 + bk) * N + col0 + bc);
        *(float4*)&Bs[bk][bc] = bv;
        __syncthreads();
#pragma unroll
        for (int kk = 0; kk < 16; ++kk) {
            float a[4], b[4];
#pragma unroll
            for (int i = 0; i < 4; ++i) a[i] = As[kk][ty * 4 + i];
#pragma unroll
            for (int j = 0; j < 4; ++j) b[j] = Bs[kk][tx * 4 + j];
#pragma unroll
            for (int i = 0; i < 4; ++i)
#pragma unroll
                for (int j = 0; j < 4; ++j) acc[i][j] += a[i] * b[j];
        }
        __syncthreads();
    }
#pragma unroll
    for (int i = 0; i < 4; ++i) {
        int r = row0 + ty * 4 + i;
        if (r < M) {
#pragma unroll
            for (int j = 0; j < 4; ++j)
                C[(size_t)r * N + col0 + tx * 4 + j] = acc[i][j];
        }
    }
}

// ---------------- MFMA GEMM, direct-from-global fragments ----------------
// A [M,K] bf16 row-major; WT [N,K] bf16 row-major (B transposed). 64x64 tile.
__global__ __launch_bounds__(256) void gemm_mfma(const unsigned short* __restrict__ A,
                                                 const unsigned short* __restrict__ WT,
                                                 float* __restrict__ C,
                                                 int M, int N, int K,
                                                 const int* __restrict__ flags) {
    if (flags[2] != 1) return;
    const int t = threadIdx.x;
    const int wave = t >> 6, lane = t & 63;
    const int l16 = lane & 15, q = lane >> 4;
    const int row0 = blockIdx.y * 64, col0 = blockIdx.x * 64;
    const int wm = (wave & 1) * 32, wn = (wave >> 1) * 32;
    const int r0 = row0 + wm + l16;
    const int r1 = r0 + 16;
    const bool g0 = r0 < M, g1 = r1 < M;
    const unsigned short* a0p = A + (size_t)(g0 ? r0 : 0) * K;
    const unsigned short* a1p = A + (size_t)(g1 ? r1 : 0) * K;
    const unsigned short* b0p = WT + (size_t)(col0 + wn + l16) * K;
    const unsigned short* b1p = b0p + (size_t)16 * K;
    f32x4 acc00 = {0.f, 0.f, 0.f, 0.f}, acc01 = acc00, acc10 = acc00, acc11 = acc00;
    for (int k0 = 0; k0 < K; k0 += 32) {
        int kq = k0 + q * 8;
        v8s a0 = *(const v8s*)(a0p + kq);
        v8s a1 = *(const v8s*)(a1p + kq);
        v8s b0 = *(const v8s*)(b0p + kq);
        v8s b1 = *(const v8s*)(b1p + kq);
        acc00 = __builtin_amdgcn_mfma_f32_16x16x32_bf16(a0, b0, acc00, 0, 0, 0);
        acc01 = __builtin_amdgcn_mfma_f32_16x16x32_bf16(a0, b1, acc01, 0, 0, 0);
        acc10 = __builtin_amdgcn_mfma_f32_16x16x32_bf16(a1, b0, acc10, 0, 0, 0);
        acc11 = __builtin_amdgcn_mfma_f32_16x16x32_bf16(a1, b1, acc11, 0, 0, 0);
    }
#pragma unroll
    for (int r = 0; r < 4; ++r) {
        int rowa = row0 + wm + q * 4 + r;
        int rowb = rowa + 16;
        if (rowa < M) {
            C[(size_t)rowa * N + col0 + wn + l16] = acc00[r];
            C[(size_t)rowa * N + col0 + wn + 16 + l16] = acc01[r];
        }
        if (rowb < M) {
            C[(size_t)rowb * N + col0 + wn + l16] = acc10[r];
            C[(size_t)rowb * N + col0 + wn + 16 + l16] = acc11[r];
        }
    }
}

// ---------------- el/er per node per head ----------------
__global__ __launch_bounds__(256) void compute_eler(const float* __restrict__ feat,
                                                    const float* __restrict__ al,
                                                    const float* __restrict__ ar,
                                                    float* __restrict__ el,
                                                    float* __restrict__ er) {
    int n = blockIdx.x;
    int h = threadIdx.x >> 6;
    int lane = threadIdx.x & 63;
    const float* f = feat + (size_t)n * 512 + h * 128;
    const float* a = al + h * 128;
    const float* r = ar + h * 128;
    float accl = f[lane] * a[lane] + f[lane + 64] * a[lane + 64];
    float accr = f[lane] * r[lane] + f[lane + 64] * r[lane + 64];
    for (int o = 32; o > 0; o >>= 1) {
        accl += __shfl_down(accl, o);
        accr += __shfl_down(accr, o);
    }
    if (lane == 0) { el[n * 4 + h] = accl; er[n * 4 + h] = accr; }
}

// ---------------- GAT softmax + aggregation per destination node ----------------
template <bool RES, bool ACT>
__global__ __launch_bounds__(256) void gat_agg(const float* __restrict__ feat,
                                               const float* __restrict__ el,
                                               const float* __restrict__ er,
                                               const int* __restrict__ off,
                                               const int* __restrict__ srcsorted,
                                               const float* __restrict__ resid,
                                               const float* __restrict__ bias,
                                               float* __restrict__ out) {
    __shared__ float4 red[256];
    __shared__ float wbuf[64 * 4];
    __shared__ int sl[64];
    const int n = blockIdx.x;
    const int tid = threadIdx.x;
    const int off0 = off[n];
    const int deg = off[n + 1] - off0;
    float4 er4 = *(const float4*)(er + n * 4);

    float m0 = -1e30f, m1 = -1e30f, m2 = -1e30f, m3 = -1e30f;
    for (int i = tid; i < deg; i += 256) {
        int s = srcsorted[off0 + i];
        float4 ev = *(const float4*)(el + s * 4);
        m0 = fmaxf(m0, lrelu(ev.x + er4.x));
        m1 = fmaxf(m1, lrelu(ev.y + er4.y));
        m2 = fmaxf(m2, lrelu(ev.z + er4.z));
        m3 = fmaxf(m3, lrelu(ev.w + er4.w));
    }
    red[tid] = make_float4(m0, m1, m2, m3);
    __syncthreads();
    for (int st = 128; st > 0; st >>= 1) {
        if (tid < st) {
            float4 a = red[tid], b = red[tid + st];
            red[tid] = make_float4(fmaxf(a.x, b.x), fmaxf(a.y, b.y),
                                   fmaxf(a.z, b.z), fmaxf(a.w, b.w));
        }
        __syncthreads();
    }
    float4 mm = red[0];
    __syncthreads();

    float s0 = 0.f, s1 = 0.f, s2 = 0.f, s3 = 0.f;
    for (int i = tid; i < deg; i += 256) {
        int s = srcsorted[off0 + i];
        float4 ev = *(const float4*)(el + s * 4);
        s0 += expf(lrelu(ev.x + er4.x) - mm.x);
        s1 += expf(lrelu(ev.y + er4.y) - mm.y);
        s2 += expf(lrelu(ev.z + er4.z) - mm.z);
        s3 += expf(lrelu(ev.w + er4.w) - mm.w);
    }
    red[tid] = make_float4(s0, s1, s2, s3);
    __syncthreads();
    for (int st = 128; st > 0; st >>= 1) {
        if (tid < st) {
            float4 a = red[tid], b = red[tid + st];
            red[tid] = make_float4(a.x + b.x, a.y + b.y, a.z + b.z, a.w + b.w);
        }
        __syncthreads();
    }
    float4 dd = red[0];
    dd.x = fmaxf(dd.x, 1e-9f); dd.y = fmaxf(dd.y, 1e-9f);
    dd.z = fmaxf(dd.z, 1e-9f); dd.w = fmaxf(dd.w, 1e-9f);
    __syncthreads();

    const int p0 = tid;
    const int p1 = tid + 256;
    const int h0 = tid >> 7;
    const int h1 = 2 + (tid >> 7);
    float acc0 = 0.f, acc1 = 0.f;
    for (int c = 0; c < deg; c += 64) {
        int cl = min(64, deg - c);
        __syncthreads();
        {
            int i = tid >> 2, h = tid & 3;
            if (i < cl) {
                int s = srcsorted[off0 + c + i];
                if (h == 0) sl[i] = s;
                float ev = el[s * 4 + h];
                float erh = (h == 0) ? er4.x : (h == 1) ? er4.y : (h == 2) ? er4.z : er4.w;
                float mh  = (h == 0) ? mm.x : (h == 1) ? mm.y : (h == 2) ? mm.z : mm.w;
                float dh  = (h == 0) ? dd.x : (h == 1) ? dd.y : (h == 2) ? dd.z : dd.w;
                wbuf[i * 4 + h] = expf(lrelu(ev + erh) - mh) / dh;
            }
        }
        __syncthreads();
        for (int i2 = 0; i2 < cl; ++i2) {
            int s = sl[i2];
            float w0 = wbuf[i2 * 4 + h0];
            float w1 = wbuf[i2 * 4 + h1];
            acc0 += w0 * feat[(size_t)s * 512 + p0];
            acc1 += w1 * feat[(size_t)s * 512 + p1];
        }
    }
    float v0 = acc0 + bias[p0];
    float v1 = acc1 + bias[p1];
    if (RES) { v0 += resid[(size_t)n * 512 + p0]; v1 += resid[(size_t)n * 512 + p1]; }
    if (ACT) { v0 = elu_f(v0); v1 = elu_f(v1); }
    out[(size_t)n * 512 + p0] = v0;
    out[(size_t)n * 512 + p1] = v1;
}

// ---------------- fallback edge MLP (round-2 proven, PQ-combined layout) ----------------
__global__ __launch_bounds__(256) void edge_mlp(const float* __restrict__ PQ,
                                                const float* __restrict__ bm0,
                                                const float* __restrict__ Wm1,
                                                const float* __restrict__ bm1,
                                                const float* __restrict__ Wm2,
                                                const float* __restrict__ bm2,
                                                const int* __restrict__ src,
                                                const int* __restrict__ dst,
                                                void* __restrict__ outv,
                                                const int* __restrict__ flags,
                                                int E) {
    if (flags[2] == 1) return;
    __shared__ float sW1[128 * 64];
    __shared__ float sW2[64];
    __shared__ float sb0[128];
    __shared__ float sb1[64];
    __shared__ float z0s[4][128];
    const int tid = threadIdx.x;
    for (int i = tid; i < 128 * 64; i += 256) sW1[i] = Wm1[i];
    if (tid < 64) { sW2[tid] = Wm2[tid]; sb1[tid] = bm1[tid]; }
    if (tid < 128) sb0[tid] = bm0[tid];
    __syncthreads();
    const int wave = tid >> 6, lane = tid & 63;
    const int gw = blockIdx.x * 4 + wave;
    const int total = gridDim.x * 4;
    const int iters = (E + total - 1) / total;
    const float b2 = bm2[0];
    const int f32out = flags[0];
    for (int it = 0; it < iters; ++it) {
        int e = gw + it * total;
        bool valid = e < E;
        if (valid) {
            int s = src[e], d = dst[e];
            float z0a = fmaxf(PQ[(size_t)s * 256 + lane] + PQ[(size_t)d * 256 + 128 + lane] + sb0[lane], 0.f);
            float z0b = fmaxf(PQ[(size_t)s * 256 + 64 + lane] + PQ[(size_t)d * 256 + 192 + lane] + sb0[64 + lane], 0.f);
            z0s[wave][lane] = z0a;
            z0s[wave][64 + lane] = z0b;
        }
        __syncthreads();
        if (valid) {
            float acc = sb1[lane];
#pragma unroll 8
            for (int k = 0; k < 128; ++k) acc += z0s[wave][k] * sW1[k * 64 + lane];
            acc = fmaxf(acc, 0.f);
            float tsum = acc * sW2[lane];
            for (int o = 32; o > 0; o >>= 1) tsum += __shfl_down(tsum, o);
            if (lane == 0) {
                float r = 1.f / (1.f + expf(-(tsum + b2)));
                if (f32out) ((float*)outv)[e] = r;
                else        ((unsigned short*)outv)[e] = f2b(r);
            }
        }
        __syncthreads();
    }
}

// ---------------- MFMA edge MLP ----------------
// 64 edges per block; z0 gather exact f32 -> bf16 hi|lo in LDS (K=256);
// z1 = z0 @ Wm1 via MFMA (Wm1T [64][256] direct from global); relu; dot Wm2; sigmoid.
__global__ __launch_bounds__(256) void edge_mfma(const float* __restrict__ PQ,
                                                 const float* __restrict__ bm0f,
                                                 const unsigned short* __restrict__ Wm1T,
                                                 const float* __restrict__ bm1f,
                                                 const float* __restrict__ wm2f,
                                                 const float* __restrict__ bm2f,
                                                 const int* __restrict__ src,
                                                 const int* __restrict__ dst,
                                                 void* __restrict__ outv,
                                                 const int* __restrict__ flags) {
    if (flags[2] != 1) return;
    __shared__ __align__(16) unsigned short zs[64][264];
    const int t = threadIdx.x;
    const int e0 = blockIdx.x * 64;
    const int c4 = (t & 31) * 4;
    float4 bb = *(const float4*)(bm0f + c4);
#pragma unroll
    for (int rep = 0; rep < 8; ++rep) {
        int el = rep * 8 + (t >> 5);
        int e = e0 + el;
        ushort4 hi = make_ushort4(0, 0, 0, 0), lo = make_ushort4(0, 0, 0, 0);
        if (e < kE) {
            int s = src[e], d = dst[e];
            float4 pv = *(const float4*)(PQ + (size_t)s * 256 + c4);
            float4 qv = *(const float4*)(PQ + (size_t)d * 256 + 128 + c4);
            float z0 = fmaxf(pv.x + qv.x + bb.x, 0.f);
            float z1 = fmaxf(pv.y + qv.y + bb.y, 0.f);
            float z2 = fmaxf(pv.z + qv.z + bb.z, 0.f);
            float z3 = fmaxf(pv.w + qv.w + bb.w, 0.f);
            hi = make_ushort4(f2b(z0), f2b(z1), f2b(z2), f2b(z3));
            lo = make_ushort4(f2b(z0 - b2f(hi.x)), f2b(z1 - b2f(hi.y)),
                              f2b(z2 - b2f(hi.z)), f2b(z3 - b2f(hi.w)));
        }
        *(ushort4*)&zs[el][c4] = hi;
        *(ushort4*)&zs[el][128 + c4] = lo;
    }
    __syncthreads();

    const int wave = t >> 6, lane = t & 63;
    const int l16 = lane & 15, q = lane >> 4;
    const int ew0 = wave * 16;
    f32x4 acc[4];
#pragma unroll
    for (int nt = 0; nt < 4; ++nt)
#pragma unroll
        for (int r = 0; r < 4; ++r) acc[nt][r] = 0.f;

#pragma unroll
    for (int ks = 0; ks < 8; ++ks) {
        int kq = ks * 32 + q * 8;
        v8s a = *(const v8s*)&zs[ew0 + l16][kq];
#pragma unroll
        for (int nt = 0; nt < 4; ++nt) {
            v8s b = *(const v8s*)(Wm1T + (size_t)(nt * 16 + l16) * 256 + kq);
            acc[nt] = __builtin_amdgcn_mfma_f32_16x16x32_bf16(a, b, acc[nt], 0, 0, 0);
        }
    }
    float b1v[4], w2v[4];
#pragma unroll
    for (int nt = 0; nt < 4; ++nt) {
        b1v[nt] = bm1f[nt * 16 + l16];
        w2v[nt] = wm2f[nt * 16 + l16];
    }
    float b2 = bm2f[0];
    const int f32out = flags[0];
#pragma unroll
    for (int r = 0; r < 4; ++r) {
        float v = 0.f;
#pragma unroll
        for (int nt = 0; nt < 4; ++nt)
            v += fmaxf(acc[nt][r] + b1v[nt], 0.f) * w2v[nt];
        v += __shfl_xor(v, 1);
        v += __shfl_xor(v, 2);
        v += __shfl_xor(v, 4);
        v += __shfl_xor(v, 8);
        if (l16 == 0) {
            int e = e0 + ew0 + q * 4 + r;
            if (e < kE) {
                float rr = 1.f / (1.f + expf(-(v + b2)));
                if (f32out) ((float*)outv)[e] = rr;
                else        ((unsigned short*)outv)[e] = f2b(rr);
            }
        }
    }
}

// ---------------- host launch ----------------
extern "C" void kernel_launch(void* const* d_in, const int* in_sizes, int n_in,
                              void* d_out, int out_size, void* d_ws, size_t ws_size,
                              hipStream_t stream) {
    (void)in_sizes; (void)n_in; (void)out_size; (void)ws_size;

    float* w = (float*)d_ws;
    size_t o = 0;
    auto alloc = [&](size_t n) { float* p = w + o; o += (n + 3) & ~size_t(3); return p; };
    // fallback f32 weights
    float* w0f  = alloc(256 * 512);
    float* w1f  = alloc(512 * 512);
    float* w2f  = alloc(512 * 512);
    float* wpqf = alloc(128 * 256);
    // small f32
    float* al0f = alloc(512); float* ar0f = alloc(512); float* b0f = alloc(512);
    float* al1f = alloc(512); float* ar1f = alloc(512); float* b1f = alloc(512);
    float* al2f = alloc(512); float* ar2f = alloc(512); float* b2f_ = alloc(512);
    float* bm0f = alloc(128); float* wm1f = alloc(128 * 64); float* bm1f = alloc(64);
    float* wm2f = alloc(64);  float* bm2f = alloc(4);
    float* elb  = alloc((size_t)kN * 4);
    float* erb  = alloc((size_t)kN * 4);
    // big buffers
    float* F  = alloc((size_t)kN * 512);
    float* H0 = alloc((size_t)kN * 512);
    float* H1 = alloc((size_t)kN * 512);
    // bf16 transposed weights
    unsigned short* W0T  = (unsigned short*)alloc(65536);    // [512][256]
    unsigned short* W1T  = (unsigned short*)alloc(262144);   // [512][1024]
    unsigned short* W2T  = (unsigned short*)alloc(262144);   // [512][1024]
    unsigned short* PQT  = (unsigned short*)alloc(32768);    // [256][256]
    unsigned short* Wm1T = (unsigned short*)alloc(8192);     // [64][256]
    // ints
    int* ip    = (int*)(w + o);
    int* flags = ip;
    int* deg   = ip + 4;
    int* cnt   = deg + kN;
    int* off   = cnt + kN;
    int* ss    = off + 10004;
    int* nsrc  = ss + kE;
    int* ndst  = nsrc + kE;

    // overlays (timeline-safe)
    float*          xf     = H1;                                   // f32 x, dead after L0
    unsigned short* Xb     = (unsigned short*)(H1 + 2560000);      // bf16 x, dead after L0
    unsigned short* AHL1   = (unsigned short*)H1;   // L1 hi/lo A, dead after L1 gemm
    unsigned short* AHL2   = (unsigned short*)H0;   // L2 hi/lo A, dead after L2 gemm
    unsigned short* AHLPQ  = (unsigned short*)H1;   // PQ hi/lo A, dead after PQ gemm
    float*          PQ     = F;                     // [10000,256] f32 (P|Q)
    float*          hmeanf = F + 2560000;           // f32 head-mean (fallback)

    dim3 blk(256);

    // 0) dtype detection + MFMA layout probe + index normalization
    detect_flags<<<dim3(1), blk, 0, stream>>>(d_in[0], d_in[2], flags);
    mfma_probe<<<dim3(1), dim3(64), 0, stream>>>(flags);
    norm_idx<<<dim3((kE + 255) / 256), blk, 0, stream>>>(d_in[1], nsrc, kE, flags);
    norm_idx<<<dim3((kE + 255) / 256), blk, 0, stream>>>(d_in[2], ndst, kE, flags);

    auto cvt = [&](int idx, float* dstp, int n) {
        cvt_any<<<dim3((n + 255) / 256), blk, 0, stream>>>(d_in[idx], dstp, n, flags);
    };
    cvt(3, w0f, 256 * 512); cvt(7, w1f, 512 * 512); cvt(11, w2f, 512 * 512);
    cvt(4, al0f, 512); cvt(5, ar0f, 512); cvt(6, b0f, 512);
    cvt(8, al1f, 512); cvt(9, ar1f, 512); cvt(10, b1f, 512);
    cvt(12, al2f, 512); cvt(13, ar2f, 512); cvt(14, b2f_, 512);
    cvt(16, bm0f, 128); cvt(17, wm1f, 128 * 64); cvt(18, bm1f, 64);
    cvt(19, wm2f, 64);  cvt(20, bm2f, 1);
    cvt(0, xf, kN * 256);
    wpq_prep<<<dim3(128, 1), blk, 0, stream>>>(d_in[15], wpqf, flags);

    // bf16 transposed weights + bf16 x
    wtprep<<<dim3((512 * 256 + 255) / 256), blk, 0, stream>>>(d_in[3], W0T, 512, 256, 256, flags);
    wtprep<<<dim3((512 * 1024 + 255) / 256), blk, 0, stream>>>(d_in[7], W1T, 512, 512, 1024, flags);
    wtprep<<<dim3((512 * 1024 + 255) / 256), blk, 0, stream>>>(d_in[11], W2T, 512, 512, 1024, flags);
    pqt_prep<<<dim3(256, 1), blk, 0, stream>>>(d_in[15], PQT, flags);
    wtprep<<<dim3((64 * 256 + 255) / 256), blk, 0, stream>>>(d_in[17], Wm1T, 64, 128, 256, flags);
    xprep<<<dim3((kN * 256 + 255) / 256), blk, 0, stream>>>(d_in[0], Xb, kN * 256, flags);

    // 1) CSR build
    zero_ints<<<dim3((2 * kN + 255) / 256), blk, 0, stream>>>(deg, 2 * kN);
    count_deg<<<dim3((kE + 255) / 256), blk, 0, stream>>>(ndst, deg, kE);
    scan_off<<<dim3(1), dim3(1024), 0, stream>>>(deg, off, kN);
    fill_csr<<<dim3((kE + 255) / 256), blk, 0, stream>>>(nsrc, ndst, off, cnt, ss, kE);

    const int gy = (kN + 63) / 64;   // 157

    // 2) Layer 0
    gemm_f32 <<<dim3(8, gy), blk, 0, stream>>>(xf, w0f, F, kN, 512, 256, flags);
    gemm_mfma<<<dim3(8, gy), blk, 0, stream>>>(Xb, W0T, F, kN, 512, 256, flags);
    compute_eler<<<dim3(kN), blk, 0, stream>>>(F, al0f, ar0f, elb, erb);
    gat_agg<false, true><<<dim3(kN), blk, 0, stream>>>(F, elb, erb, off, ss, nullptr, b0f, H0);

    // 3) Layer 1 (residual, ELU)
    hilo512<<<dim3((kN * 512 + 255) / 256), blk, 0, stream>>>(H0, AHL1, kN * 512);
    gemm_f32 <<<dim3(8, gy), blk, 0, stream>>>(H0, w1f, F, kN, 512, 512, flags);
    gemm_mfma<<<dim3(8, gy), blk, 0, stream>>>(AHL1, W1T, F, kN, 512, 1024, flags);
    compute_eler<<<dim3(kN), blk, 0, stream>>>(F, al1f, ar1f, elb, erb);
    gat_agg<true, true><<<dim3(kN), blk, 0, stream>>>(F, elb, erb, off, ss, H0, b1f, H1);

    // 4) Layer 2 (residual, no act)
    hilo512<<<dim3((kN * 512 + 255) / 256), blk, 0, stream>>>(H1, AHL2, kN * 512);
    gemm_f32 <<<dim3(8, gy), blk, 0, stream>>>(H1, w2f, F, kN, 512, 512, flags);
    gemm_mfma<<<dim3(8, gy), blk, 0, stream>>>(AHL2, W2T, F, kN, 512, 1024, flags);
    compute_eler<<<dim3(kN), blk, 0, stream>>>(F, al2f, ar2f, elb, erb);
    gat_agg<true, false><<<dim3(kN), blk, 0, stream>>>(F, elb, erb, off, ss, H1, b2f_, H0);

    // 5) head mean + PQ = [P|Q]
    mean_heads<<<dim3(kN), dim3(128), 0, stream>>>(H0, hmeanf);
    meanhilo<<<dim3(kN), dim3(128), 0, stream>>>(H0, AHLPQ);
    gemm_f32 <<<dim3(4, gy), blk, 0, stream>>>(hmeanf, wpqf, PQ, kN, 256, 128, flags);
    gemm_mfma<<<dim3(4, gy), blk, 0, stream>>>(AHLPQ, PQT, PQ, kN, 256, 256, flags);

    // 6) edge MLP + sigmoid
    edge_mlp <<<dim3(1024), blk, 0, stream>>>(PQ, bm0f, wm1f, bm1f, wm2f, bm2f,
                                              nsrc, ndst, d_out, flags, kE);
    edge_mfma<<<dim3((kE + 63) / 64), blk, 0, stream>>>(PQ, bm0f, Wm1T, bm1f, wm2f, bm2f,
                                                        nsrc, ndst, d_out, flags);
}

// Round 5
// 546.119 us; speedup vs baseline: 1.3609x; 1.2606x over previous
//
#include <hip/hip_runtime.h>
#include <hip/hip_bf16.h>
#include <math.h>

constexpr int kN = 10000;   // nodes
constexpr int kE = 160000;  // edges
constexpr float kSlope = 0.2f;

typedef short v8s __attribute__((ext_vector_type(8)));
typedef float f32x4 __attribute__((ext_vector_type(4)));

__device__ __forceinline__ float lrelu(float x) { return x > 0.f ? x : kSlope * x; }
__device__ __forceinline__ float elu_f(float x) { return x > 0.f ? x : (expf(x) - 1.f); }
__device__ __forceinline__ float b2f(unsigned short u) {
    return __uint_as_float(((unsigned)u) << 16);
}
__device__ __forceinline__ unsigned short f2b(float f) {   // RNE f32->bf16
    unsigned u = __float_as_uint(f);
    return (unsigned short)((u + 0x7FFFu + ((u >> 16) & 1u)) >> 16);
}

// ---------------- runtime dtype detection ----------------
__global__ void detect_flags(const void* __restrict__ x, const void* __restrict__ dsti,
                             int* __restrict__ flags) {
    __shared__ int sb[2];
    int tid = threadIdx.x;
    if (tid == 0) { sb[0] = 0; sb[1] = 0; }
    __syncthreads();
    const unsigned short* xb = (const unsigned short*)x;
    int big = 0;
    for (int i = tid; i < 4096; i += 256) {
        float v = b2f(xb[i]);
        if (!(fabsf(v) <= 1e4f)) big = 1;
    }
    const int* d32 = (const int*)dsti;
    int hi = 0;
    for (int i = tid; i < 4096; i += 256) hi |= d32[2 * i + 1];
    if (big) atomicOr(&sb[0], 1);
    if (hi)  atomicOr(&sb[1], 1);
    __syncthreads();
    if (tid == 0) { flags[0] = sb[0]; flags[1] = sb[1] ? 0 : 1; }
}

__global__ void zero_ints(int* __restrict__ p, int n) {
    int i = blockIdx.x * 256 + threadIdx.x;
    if (i < n) p[i] = 0;
}

__global__ void norm_idx(const void* __restrict__ in, int* __restrict__ out, int n,
                         const int* __restrict__ flags) {
    int i = blockIdx.x * 256 + threadIdx.x;
    if (i >= n) return;
    int v = flags[1] ? (int)((const long long*)in)[i] : ((const int*)in)[i];
    out[i] = ((unsigned)v < (unsigned)kN) ? v : 0;
}

__global__ void cvt_any(const void* __restrict__ in, float* __restrict__ out, int n,
                        const int* __restrict__ flags) {
    int i = blockIdx.x * 256 + threadIdx.x;
    if (i >= n) return;
    if (flags[0]) out[i] = ((const float*)in)[i];
    else          out[i] = b2f(((const unsigned short*)in)[i]);
}

__global__ void xprep(const void* __restrict__ in, unsigned short* __restrict__ out, int n,
                      const int* __restrict__ flags) {
    int i = blockIdx.x * 256 + threadIdx.x;
    if (i >= n) return;
    out[i] = flags[0] ? f2b(((const float*)in)[i]) : ((const unsigned short*)in)[i];
}

// f32 [M,512] -> bf16 hi|lo [M,1024]
__global__ void hilo512(const float* __restrict__ in, unsigned short* __restrict__ out, int total) {
    int i = blockIdx.x * 256 + threadIdx.x;
    if (i >= total) return;
    int row = i >> 9, c = i & 511;
    float v = in[i];
    unsigned short h = f2b(v);
    out[(size_t)row * 1024 + c] = h;
    out[(size_t)row * 1024 + 512 + c] = f2b(v - b2f(h));
}

// head-mean f32 [N,4,128] -> bf16 hi|lo [N,256]
__global__ void meanhilo(const float* __restrict__ in, unsigned short* __restrict__ out) {
    int n = blockIdx.x, c = threadIdx.x;   // 128 threads
    const float* r = in + (size_t)n * 512;
    float v = 0.25f * (r[c] + r[128 + c] + r[256 + c] + r[384 + c]);
    unsigned short h = f2b(v);
    out[(size_t)n * 256 + c] = h;
    out[(size_t)n * 256 + 128 + c] = f2b(v - b2f(h));
}

// WT[n*Kout + k] = W[(k % Ksrc)*N + n]  (bf16 transpose, optional hi/lo K-doubling)
__global__ void wtprep(const void* __restrict__ W, unsigned short* __restrict__ WT,
                       int N, int Ksrc, int Kout, const int* __restrict__ flags) {
    int idx = blockIdx.x * 256 + threadIdx.x;
    if (idx >= N * Kout) return;
    int n = idx / Kout, k = idx - n * Kout;
    int srcidx = (k % Ksrc) * N + n;
    unsigned short v = flags[0] ? f2b(((const float*)W)[srcidx])
                                : ((const unsigned short*)W)[srcidx];
    WT[(size_t)n * Kout + k] = v;
}

// PQT[n*256 + k]: combined P|Q weight transpose
__global__ void pqt_prep(const void* __restrict__ Wm0, unsigned short* __restrict__ PQT,
                         const int* __restrict__ flags) {
    int idx = blockIdx.x * 256 + threadIdx.x;
    if (idx >= 256 * 256) return;
    int n = idx >> 8, k = idx & 255;
    int srcidx = ((k & 127) + ((n < 128) ? 0 : 128)) * 128 + (n & 127);
    unsigned short v = flags[0] ? f2b(((const float*)Wm0)[srcidx])
                                : ((const unsigned short*)Wm0)[srcidx];
    PQT[idx] = v;
}

// ---------------- CSR build ----------------
__global__ void count_deg(const int* __restrict__ dst, int* __restrict__ deg, int n) {
    int i = blockIdx.x * 256 + threadIdx.x;
    if (i < n) atomicAdd(&deg[dst[i]], 1);
}

__global__ __launch_bounds__(1024) void scan_off(const int* __restrict__ deg,
                                                 int* __restrict__ off, int n) {
    __shared__ int s[1024];
    int tid = threadIdx.x;
    int per = (n + 1023) >> 10;
    int base = tid * per;
    int sum = 0;
    for (int i = 0; i < per; ++i) { int j = base + i; if (j < n) sum += deg[j]; }
    s[tid] = sum;
    __syncthreads();
    for (int d = 1; d < 1024; d <<= 1) {
        int v = (tid >= d) ? s[tid - d] : 0;
        __syncthreads();
        s[tid] += v;
        __syncthreads();
    }
    int run = (tid > 0) ? s[tid - 1] : 0;
    for (int i = 0; i < per; ++i) {
        int j = base + i;
        if (j < n) { off[j] = run; run += deg[j]; }
    }
    if (tid == 0) off[n] = s[1023];
}

__global__ void fill_csr(const int* __restrict__ src, const int* __restrict__ dst,
                         const int* __restrict__ off, int* __restrict__ cnt,
                         int* __restrict__ srcsorted, int n) {
    int i = blockIdx.x * 256 + threadIdx.x;
    if (i < n) {
        int d = dst[i];
        int pos = off[d] + atomicAdd(&cnt[d], 1);
        if (pos < kE) srcsorted[pos] = src[i];
    }
}

// ---------------- LDS-staged MFMA GEMM ----------------
// A [M,K] bf16 row-major; WT [N,K] bf16 row-major. C [M,N] f32.
// Tile 64(M) x 128(N), 256 threads; wave covers 32x64 (wm=(w&1)*32, wn=(w>>1)*64).
// LDS k-chunk-major with XOR swizzle: staging writes conflict-free, frag reads 2-way (free).
// Fragment math identical to the HW-verified round-4 direct-global version.
__global__ __launch_bounds__(256) void gemm_mfma(const unsigned short* __restrict__ A,
                                                 const unsigned short* __restrict__ WT,
                                                 float* __restrict__ C,
                                                 int M, int N, int K) {
    __shared__ __align__(16) unsigned short As[4][64][8];    // [k8][m^swz][j]  4KB
    __shared__ __align__(16) unsigned short Bs[4][128][8];   // [k8][n^swz][j]  8KB
    const int t = threadIdx.x;
    const int wave = t >> 6, lane = t & 63;
    const int l16 = lane & 15, q = lane >> 4;
    const int row0 = blockIdx.y * 64, col0 = blockIdx.x * 128;
    const int wm = (wave & 1) * 32, wn = (wave >> 1) * 64;
    const int am = t >> 2, ak8 = t & 3;
    const int sw = ak8 * 4;

    const unsigned short* aptr = A + (size_t)min(row0 + am, M - 1) * K + ak8 * 8;
    const unsigned short* bptr0 = WT + (size_t)(col0 + am) * K + ak8 * 8;
    const unsigned short* bptr1 = bptr0 + (size_t)64 * K;

    uint4 ga  = *(const uint4*)aptr;
    uint4 gb0 = *(const uint4*)bptr0;
    uint4 gb1 = *(const uint4*)bptr1;

    f32x4 acc[2][4];
#pragma unroll
    for (int mt = 0; mt < 2; ++mt)
#pragma unroll
        for (int nt = 0; nt < 4; ++nt)
#pragma unroll
            for (int r = 0; r < 4; ++r) acc[mt][nt][r] = 0.f;

    for (int k0 = 0; k0 < K; k0 += 32) {
        __syncthreads();
        *(uint4*)&As[ak8][am ^ sw][0] = ga;
        *(uint4*)&Bs[ak8][am ^ sw][0] = gb0;
        *(uint4*)&Bs[ak8][(am + 64) ^ sw][0] = gb1;
        __syncthreads();
        if (k0 + 32 < K) {
            ga  = *(const uint4*)(aptr + k0 + 32);
            gb0 = *(const uint4*)(bptr0 + k0 + 32);
            gb1 = *(const uint4*)(bptr1 + k0 + 32);
        }
        v8s af[2], bf[4];
        const int qs = q * 4;
#pragma unroll
        for (int mt = 0; mt < 2; ++mt)
            af[mt] = *(const v8s*)&As[q][(wm + mt * 16 + l16) ^ qs][0];
#pragma unroll
        for (int nt = 0; nt < 4; ++nt)
            bf[nt] = *(const v8s*)&Bs[q][(wn + nt * 16 + l16) ^ qs][0];
#pragma unroll
        for (int mt = 0; mt < 2; ++mt)
#pragma unroll
            for (int nt = 0; nt < 4; ++nt)
                acc[mt][nt] = __builtin_amdgcn_mfma_f32_16x16x32_bf16(af[mt], bf[nt],
                                                                      acc[mt][nt], 0, 0, 0);
    }
#pragma unroll
    for (int mt = 0; mt < 2; ++mt)
#pragma unroll
        for (int r = 0; r < 4; ++r) {
            int row = row0 + wm + mt * 16 + q * 4 + r;
            if (row < M) {
#pragma unroll
                for (int nt = 0; nt < 4; ++nt)
                    C[(size_t)row * N + col0 + wn + nt * 16 + l16] = acc[mt][nt][r];
            }
        }
}

// ---------------- el/er per node per head ----------------
__global__ __launch_bounds__(256) void compute_eler(const float* __restrict__ feat,
                                                    const float* __restrict__ al,
                                                    const float* __restrict__ ar,
                                                    float* __restrict__ el,
                                                    float* __restrict__ er) {
    int n = blockIdx.x;
    int h = threadIdx.x >> 6;
    int lane = threadIdx.x & 63;
    const float* f = feat + (size_t)n * 512 + h * 128;
    const float* a = al + h * 128;
    const float* r = ar + h * 128;
    float accl = f[lane] * a[lane] + f[lane + 64] * a[lane + 64];
    float accr = f[lane] * r[lane] + f[lane + 64] * r[lane + 64];
    for (int o = 32; o > 0; o >>= 1) {
        accl += __shfl_down(accl, o);
        accr += __shfl_down(accr, o);
    }
    if (lane == 0) { el[n * 4 + h] = accl; er[n * 4 + h] = accr; }
}

// ---------------- GAT softmax + aggregation: one wave per destination node ----------------
template <bool RES, bool ACT>
__global__ __launch_bounds__(256) void gat_agg(const float* __restrict__ feat,
                                               const float* __restrict__ el,
                                               const float* __restrict__ er,
                                               const int* __restrict__ off,
                                               const int* __restrict__ ss,
                                               const float* __restrict__ resid,
                                               const float* __restrict__ bias,
                                               float* __restrict__ out) {
    const int node = blockIdx.x * 4 + (threadIdx.x >> 6);
    const int lane = threadIdx.x & 63;
    if (node >= kN) return;
    const int off0 = off[node];
    const int deg = off[node + 1] - off0;
    float4 er4 = *(const float4*)(er + node * 4);

    // pass 1: per-head max over incoming edges
    float m0 = -1e30f, m1 = -1e30f, m2 = -1e30f, m3 = -1e30f;
    for (int i = lane; i < deg; i += 64) {
        int s = ss[off0 + i];
        float4 ev = *(const float4*)(el + s * 4);
        m0 = fmaxf(m0, lrelu(ev.x + er4.x));
        m1 = fmaxf(m1, lrelu(ev.y + er4.y));
        m2 = fmaxf(m2, lrelu(ev.z + er4.z));
        m3 = fmaxf(m3, lrelu(ev.w + er4.w));
    }
    for (int o = 1; o < 64; o <<= 1) {
        m0 = fmaxf(m0, __shfl_xor(m0, o));
        m1 = fmaxf(m1, __shfl_xor(m1, o));
        m2 = fmaxf(m2, __shfl_xor(m2, o));
        m3 = fmaxf(m3, __shfl_xor(m3, o));
    }
    // pass 2: per-head sum of exp
    float s0 = 0.f, s1 = 0.f, s2 = 0.f, s3 = 0.f;
    for (int i = lane; i < deg; i += 64) {
        int s = ss[off0 + i];
        float4 ev = *(const float4*)(el + s * 4);
        s0 += expf(lrelu(ev.x + er4.x) - m0);
        s1 += expf(lrelu(ev.y + er4.y) - m1);
        s2 += expf(lrelu(ev.z + er4.z) - m2);
        s3 += expf(lrelu(ev.w + er4.w) - m3);
    }
    for (int o = 1; o < 64; o <<= 1) {
        s0 += __shfl_xor(s0, o);
        s1 += __shfl_xor(s1, o);
        s2 += __shfl_xor(s2, o);
        s3 += __shfl_xor(s3, o);
    }
    const int head = lane >> 4;                       // (lane*8)/128
    const float mh  = (head == 0) ? m0 : (head == 1) ? m1 : (head == 2) ? m2 : m3;
    const float dh  = fmaxf((head == 0) ? s0 : (head == 1) ? s1 : (head == 2) ? s2 : s3, 1e-9f);
    const float erh = (head == 0) ? er4.x : (head == 1) ? er4.y : (head == 2) ? er4.z : er4.w;

    // pass 3: weighted aggregation; lane owns cols c0..c0+7
    const int c0 = lane * 8;
    float acc[8] = {};
    for (int j = 0; j < deg; ++j) {
        int s = ss[off0 + j];
        float e = el[s * 4 + head];
        float wgt = expf(lrelu(e + erh) - mh) / dh;
        const float* fp = feat + (size_t)s * 512 + c0;
        float4 f0 = *(const float4*)fp;
        float4 f1 = *(const float4*)(fp + 4);
        acc[0] += wgt * f0.x; acc[1] += wgt * f0.y;
        acc[2] += wgt * f0.z; acc[3] += wgt * f0.w;
        acc[4] += wgt * f1.x; acc[5] += wgt * f1.y;
        acc[6] += wgt * f1.z; acc[7] += wgt * f1.w;
    }
    float4 b0 = *(const float4*)(bias + c0);
    float4 b1 = *(const float4*)(bias + c0 + 4);
    float v[8] = {acc[0] + b0.x, acc[1] + b0.y, acc[2] + b0.z, acc[3] + b0.w,
                  acc[4] + b1.x, acc[5] + b1.y, acc[6] + b1.z, acc[7] + b1.w};
    if (RES) {
        const float* rp = resid + (size_t)node * 512 + c0;
        float4 r0 = *(const float4*)rp;
        float4 r1 = *(const float4*)(rp + 4);
        v[0] += r0.x; v[1] += r0.y; v[2] += r0.z; v[3] += r0.w;
        v[4] += r1.x; v[5] += r1.y; v[6] += r1.z; v[7] += r1.w;
    }
    if (ACT) {
#pragma unroll
        for (int r = 0; r < 8; ++r) v[r] = elu_f(v[r]);
    }
    float* op = out + (size_t)node * 512 + c0;
    *(float4*)op       = make_float4(v[0], v[1], v[2], v[3]);
    *(float4*)(op + 4) = make_float4(v[4], v[5], v[6], v[7]);
}

// ---------------- MFMA edge MLP (HW-verified round-4 version) ----------------
__global__ __launch_bounds__(256) void edge_mfma(const float* __restrict__ PQ,
                                                 const float* __restrict__ bm0f,
                                                 const unsigned short* __restrict__ Wm1T,
                                                 const float* __restrict__ bm1f,
                                                 const float* __restrict__ wm2f,
                                                 const float* __restrict__ bm2f,
                                                 const int* __restrict__ src,
                                                 const int* __restrict__ dst,
                                                 void* __restrict__ outv,
                                                 const int* __restrict__ flags) {
    __shared__ __align__(16) unsigned short zs[64][264];
    const int t = threadIdx.x;
    const int e0 = blockIdx.x * 64;
    const int c4 = (t & 31) * 4;
    float4 bb = *(const float4*)(bm0f + c4);
#pragma unroll
    for (int rep = 0; rep < 8; ++rep) {
        int el = rep * 8 + (t >> 5);
        int e = e0 + el;
        ushort4 hi = make_ushort4(0, 0, 0, 0), lo = make_ushort4(0, 0, 0, 0);
        if (e < kE) {
            int s = src[e], d = dst[e];
            float4 pv = *(const float4*)(PQ + (size_t)s * 256 + c4);
            float4 qv = *(const float4*)(PQ + (size_t)d * 256 + 128 + c4);
            float z0 = fmaxf(pv.x + qv.x + bb.x, 0.f);
            float z1 = fmaxf(pv.y + qv.y + bb.y, 0.f);
            float z2 = fmaxf(pv.z + qv.z + bb.z, 0.f);
            float z3 = fmaxf(pv.w + qv.w + bb.w, 0.f);
            hi = make_ushort4(f2b(z0), f2b(z1), f2b(z2), f2b(z3));
            lo = make_ushort4(f2b(z0 - b2f(hi.x)), f2b(z1 - b2f(hi.y)),
                              f2b(z2 - b2f(hi.z)), f2b(z3 - b2f(hi.w)));
        }
        *(ushort4*)&zs[el][c4] = hi;
        *(ushort4*)&zs[el][128 + c4] = lo;
    }
    __syncthreads();

    const int wave = t >> 6, lane = t & 63;
    const int l16 = lane & 15, q = lane >> 4;
    const int ew0 = wave * 16;
    f32x4 acc[4];
#pragma unroll
    for (int nt = 0; nt < 4; ++nt)
#pragma unroll
        for (int r = 0; r < 4; ++r) acc[nt][r] = 0.f;

#pragma unroll
    for (int ks = 0; ks < 8; ++ks) {
        int kq = ks * 32 + q * 8;
        v8s a = *(const v8s*)&zs[ew0 + l16][kq];
#pragma unroll
        for (int nt = 0; nt < 4; ++nt) {
            v8s b = *(const v8s*)(Wm1T + (size_t)(nt * 16 + l16) * 256 + kq);
            acc[nt] = __builtin_amdgcn_mfma_f32_16x16x32_bf16(a, b, acc[nt], 0, 0, 0);
        }
    }
    float b1v[4], w2v[4];
#pragma unroll
    for (int nt = 0; nt < 4; ++nt) {
        b1v[nt] = bm1f[nt * 16 + l16];
        w2v[nt] = wm2f[nt * 16 + l16];
    }
    float b2 = bm2f[0];
    const int f32out = flags[0];
#pragma unroll
    for (int r = 0; r < 4; ++r) {
        float v = 0.f;
#pragma unroll
        for (int nt = 0; nt < 4; ++nt)
            v += fmaxf(acc[nt][r] + b1v[nt], 0.f) * w2v[nt];
        v += __shfl_xor(v, 1);
        v += __shfl_xor(v, 2);
        v += __shfl_xor(v, 4);
        v += __shfl_xor(v, 8);
        if (l16 == 0) {
            int e = e0 + ew0 + q * 4 + r;
            if (e < kE) {
                float rr = 1.f / (1.f + expf(-(v + b2)));
                if (f32out) ((float*)outv)[e] = rr;
                else        ((unsigned short*)outv)[e] = f2b(rr);
            }
        }
    }
}

// ---------------- host launch ----------------
extern "C" void kernel_launch(void* const* d_in, const int* in_sizes, int n_in,
                              void* d_out, int out_size, void* d_ws, size_t ws_size,
                              hipStream_t stream) {
    (void)in_sizes; (void)n_in; (void)out_size; (void)ws_size;

    float* w = (float*)d_ws;
    size_t o = 0;
    auto alloc = [&](size_t n) { float* p = w + o; o += (n + 3) & ~size_t(3); return p; };
    float* al0f = alloc(512); float* ar0f = alloc(512); float* b0f = alloc(512);
    float* al1f = alloc(512); float* ar1f = alloc(512); float* b1f = alloc(512);
    float* al2f = alloc(512); float* ar2f = alloc(512); float* b2f_ = alloc(512);
    float* bm0f = alloc(128); float* bm1f = alloc(64);
    float* wm2f = alloc(64);  float* bm2f = alloc(4);
    float* elb  = alloc((size_t)kN * 4);
    float* erb  = alloc((size_t)kN * 4);
    float* F  = alloc((size_t)kN * 512);
    float* H0 = alloc((size_t)kN * 512);
    float* H1 = alloc((size_t)kN * 512);
    unsigned short* W0T  = (unsigned short*)alloc(65536);    // [512][256]
    unsigned short* W1T  = (unsigned short*)alloc(262144);   // [512][1024]
    unsigned short* W2T  = (unsigned short*)alloc(262144);   // [512][1024]
    unsigned short* PQT  = (unsigned short*)alloc(32768);    // [256][256]
    unsigned short* Wm1T = (unsigned short*)alloc(8192);     // [64][256]
    int* ip    = (int*)(w + o);
    int* flags = ip;
    int* deg   = ip + 4;
    int* cnt   = deg + kN;
    int* off   = cnt + kN;
    int* ss    = off + 10004;
    int* nsrc  = ss + kE;
    int* ndst  = nsrc + kE;

    // overlays (timeline-safe)
    unsigned short* Xb    = (unsigned short*)H1;   // bf16 x [10000,256], dead after L0 gemm
    unsigned short* AHL1  = (unsigned short*)H1;   // hi/lo [10000,1024], dead after L1 gemm
    unsigned short* AHL2  = (unsigned short*)H0;   // hi/lo [10000,1024], dead after L2 gemm
    unsigned short* AHLPQ = (unsigned short*)H1;   // hi/lo [10000,256], dead after PQ gemm
    float*          PQ    = F;                     // [10000,256] f32 (P|Q)

    dim3 blk(256);

    // 0) dtype detection + index normalization
    detect_flags<<<dim3(1), blk, 0, stream>>>(d_in[0], d_in[2], flags);
    norm_idx<<<dim3((kE + 255) / 256), blk, 0, stream>>>(d_in[1], nsrc, kE, flags);
    norm_idx<<<dim3((kE + 255) / 256), blk, 0, stream>>>(d_in[2], ndst, kE, flags);

    auto cvt = [&](int idx, float* dstp, int n) {
        cvt_any<<<dim3((n + 255) / 256), blk, 0, stream>>>(d_in[idx], dstp, n, flags);
    };
    cvt(4, al0f, 512); cvt(5, ar0f, 512); cvt(6, b0f, 512);
    cvt(8, al1f, 512); cvt(9, ar1f, 512); cvt(10, b1f, 512);
    cvt(12, al2f, 512); cvt(13, ar2f, 512); cvt(14, b2f_, 512);
    cvt(16, bm0f, 128); cvt(18, bm1f, 64);
    cvt(19, wm2f, 64);  cvt(20, bm2f, 1);

    // bf16 transposed weights + bf16 x
    wtprep<<<dim3((512 * 256 + 255) / 256), blk, 0, stream>>>(d_in[3], W0T, 512, 256, 256, flags);
    wtprep<<<dim3((512 * 1024 + 255) / 256), blk, 0, stream>>>(d_in[7], W1T, 512, 512, 1024, flags);
    wtprep<<<dim3((512 * 1024 + 255) / 256), blk, 0, stream>>>(d_in[11], W2T, 512, 512, 1024, flags);
    pqt_prep<<<dim3(256, 1), blk, 0, stream>>>(d_in[15], PQT, flags);
    wtprep<<<dim3((64 * 256 + 255) / 256), blk, 0, stream>>>(d_in[17], Wm1T, 64, 128, 256, flags);
    xprep<<<dim3((kN * 256 + 255) / 256), blk, 0, stream>>>(d_in[0], Xb, kN * 256, flags);

    // 1) CSR build
    zero_ints<<<dim3((2 * kN + 255) / 256), blk, 0, stream>>>(deg, 2 * kN);
    count_deg<<<dim3((kE + 255) / 256), blk, 0, stream>>>(ndst, deg, kE);
    scan_off<<<dim3(1), dim3(1024), 0, stream>>>(deg, off, kN);
    fill_csr<<<dim3((kE + 255) / 256), blk, 0, stream>>>(nsrc, ndst, off, cnt, ss, kE);

    const int gy = (kN + 63) / 64;      // 157 row tiles
    const int ga = (kN + 3) / 4;        // 2500 agg blocks

    // 2) Layer 0: feat = x @ W0 (bit-exact bf16 inputs)
    gemm_mfma<<<dim3(4, gy), blk, 0, stream>>>(Xb, W0T, F, kN, 512, 256);
    compute_eler<<<dim3(kN), blk, 0, stream>>>(F, al0f, ar0f, elb, erb);
    gat_agg<false, true><<<dim3(ga), blk, 0, stream>>>(F, elb, erb, off, ss, nullptr, b0f, H0);

    // 3) Layer 1 (residual, ELU): hi/lo(H0) @ W1, stacked K=1024
    hilo512<<<dim3((kN * 512 + 255) / 256), blk, 0, stream>>>(H0, AHL1, kN * 512);
    gemm_mfma<<<dim3(4, gy), blk, 0, stream>>>(AHL1, W1T, F, kN, 512, 1024);
    compute_eler<<<dim3(kN), blk, 0, stream>>>(F, al1f, ar1f, elb, erb);
    gat_agg<true, true><<<dim3(ga), blk, 0, stream>>>(F, elb, erb, off, ss, H0, b1f, H1);

    // 4) Layer 2 (residual, no act)
    hilo512<<<dim3((kN * 512 + 255) / 256), blk, 0, stream>>>(H1, AHL2, kN * 512);
    gemm_mfma<<<dim3(4, gy), blk, 0, stream>>>(AHL2, W2T, F, kN, 512, 1024);
    compute_eler<<<dim3(kN), blk, 0, stream>>>(F, al2f, ar2f, elb, erb);
    gat_agg<true, false><<<dim3(ga), blk, 0, stream>>>(F, elb, erb, off, ss, H1, b2f_, H0);

    // 5) head mean (hi/lo) + PQ = [P|Q] = hmean @ [Wm0_top | Wm0_bot], K=256
    meanhilo<<<dim3(kN), dim3(128), 0, stream>>>(H0, AHLPQ);
    gemm_mfma<<<dim3(2, gy), blk, 0, stream>>>(AHLPQ, PQT, PQ, kN, 256, 256);

    // 6) fused edge MLP (MFMA) + sigmoid
    edge_mfma<<<dim3((kE + 63) / 64), blk, 0, stream>>>(PQ, bm0f, Wm1T, bm1f, wm2f, bm2f,
                                                        nsrc, ndst, d_out, flags);
}